// Round 1
// baseline (191.636 us; speedup 1.0000x reference)
//
#include <hip/hip_runtime.h>
#include <cstdint>
#include <cstddef>

typedef __bf16 bf16;
typedef __bf16 bf16x4 __attribute__((ext_vector_type(4)));
typedef __bf16 bf16x8 __attribute__((ext_vector_type(8)));
typedef float f32x4 __attribute__((ext_vector_type(4)));

typedef const __attribute__((address_space(1))) void* gas_ptr;
typedef __attribute__((address_space(3))) void* las_ptr;

#define GLOAD_LDS16(g, l) __builtin_amdgcn_global_load_lds((gas_ptr)(g), (las_ptr)(l), 16, 0, 0)

// ---------------- f32 -> bf16 convert (vectorized, grid-stride) ----------------
__global__ void cvt_f32_bf16(const float* __restrict__ in, bf16* __restrict__ out, int n4) {
  int i = blockIdx.x * blockDim.x + threadIdx.x;
  int stride = gridDim.x * blockDim.x;
  for (; i < n4; i += stride) {
    float4 v = reinterpret_cast<const float4*>(in)[i];
    bf16x4 o;
    o[0] = (bf16)v.x; o[1] = (bf16)v.y; o[2] = (bf16)v.z; o[3] = (bf16)v.w;
    reinterpret_cast<bf16x4*>(out)[i] = o;
  }
}

// ---------------- GEMM: C[M,N] = A[M,K] * B[N,K]^T  (both K-contiguous) --------
// MODE 0: QKV epilogue -> scatter to q[b,h,n,d], k[b,h,n,d], vT[b,h,d,n] (bf16)
// MODE 1: FC epilogue  -> out[m,e] = acc + bias[e] (f32)
template <int MODE>
__global__ __launch_bounds__(256, 2) void gemm_bt(
    const bf16* __restrict__ A, const bf16* __restrict__ B,
    int M, int N, int K,
    bf16* __restrict__ qb, bf16* __restrict__ kb, bf16* __restrict__ vtb,
    float* __restrict__ out, const float* __restrict__ bias) {
  constexpr int BK = 32;
  __shared__ bf16 ldsA[128 * BK];
  __shared__ bf16 ldsB[128 * BK];
  const int tid = threadIdx.x;
  const int l = tid & 63;
  const int w = tid >> 6;      // wave 0..3 (2x2)
  const int wr = w >> 1, wc = w & 1;
  const int lr = l & 15, lg = l >> 4;
  const int brow = blockIdx.x * 128;
  const int bcol = blockIdx.y * 128;

  // staging: thread t covers 16B at lds byte t*16 (wave-uniform base + lane*16)
  const int srow = tid >> 2;
  const int scol = (tid & 3) * 8;
  const bf16* Ag0 = A + (size_t)(brow + srow) * K + scol;
  const bf16* Ag1 = A + (size_t)(brow + 64 + srow) * K + scol;
  const bf16* Bg0 = B + (size_t)(bcol + srow) * K + scol;
  const bf16* Bg1 = B + (size_t)(bcol + 64 + srow) * K + scol;
  bf16* la0 = &ldsA[tid * 8];
  bf16* la1 = &ldsA[2048 + tid * 8];
  bf16* lb0 = &ldsB[tid * 8];
  bf16* lb1 = &ldsB[2048 + tid * 8];

  f32x4 acc[4][4] = {};

  for (int k0 = 0; k0 < K; k0 += BK) {
    GLOAD_LDS16(Ag0 + k0, la0);
    GLOAD_LDS16(Ag1 + k0, la1);
    GLOAD_LDS16(Bg0 + k0, lb0);
    GLOAD_LDS16(Bg1 + k0, lb1);
    __syncthreads();
    bf16x8 af[4], bfr[4];
#pragma unroll
    for (int mi = 0; mi < 4; mi++)
      af[mi] = *reinterpret_cast<const bf16x8*>(&ldsA[(wr * 64 + mi * 16 + lr) * BK + lg * 8]);
#pragma unroll
    for (int ni = 0; ni < 4; ni++)
      bfr[ni] = *reinterpret_cast<const bf16x8*>(&ldsB[(wc * 64 + ni * 16 + lr) * BK + lg * 8]);
#pragma unroll
    for (int mi = 0; mi < 4; mi++)
#pragma unroll
      for (int ni = 0; ni < 4; ni++)
        acc[mi][ni] = __builtin_amdgcn_mfma_f32_16x16x32_bf16(af[mi], bfr[ni], acc[mi][ni], 0, 0, 0);
    __syncthreads();
  }

  // epilogue: C frag mapping col = lr, row = lg*4 + r
#pragma unroll
  for (int mi = 0; mi < 4; mi++) {
#pragma unroll
    for (int r = 0; r < 4; r++) {
      const int m = brow + wr * 64 + mi * 16 + lg * 4 + r;
      const int bb = m >> 10;        // batch
      const int npos = m & 1023;     // sequence pos
#pragma unroll
      for (int ni = 0; ni < 4; ni++) {
        const int e = bcol + wc * 64 + ni * 16 + lr;
        const float v = acc[mi][ni][r];
        if (MODE == 1) {
          out[(size_t)m * N + e] = v + bias[e];
        } else {
          if (e < 768) {
            const int h = e >> 6, d = e & 63;
            qb[(size_t)(bb * 12 + h) * 65536 + npos * 64 + d] = (bf16)v;
          } else if (e < 1536) {
            const int ee = e - 768;
            const int h = ee >> 6, d = ee & 63;
            kb[(size_t)(bb * 12 + h) * 65536 + npos * 64 + d] = (bf16)v;
          } else {
            const int ee = e - 1536;
            const int h = ee >> 6, d = ee & 63;
            vtb[(size_t)(bb * 12 + h) * 65536 + d * 1024 + npos] = (bf16)v;
          }
        }
      }
    }
  }
}

// ---------------- Flash attention -------------------------------------------
// Q,K: [96][1024][64] bf16 ; Vt: [96][64][1024] bf16 ; Out: [8][1024][768] bf16
// grid (8 q-tiles, 96 heads), 256 threads = 4 waves, each wave owns 32 q rows.
__global__ __launch_bounds__(256, 2) void attn_kernel(
    const bf16* __restrict__ Q, const bf16* __restrict__ K,
    const bf16* __restrict__ Vt, bf16* __restrict__ Out) {
  __shared__ bf16 P_lds[4][32][136];   // per-wave P tile, +8 pad vs 128
  const int tid = threadIdx.x;
  const int l = tid & 63;
  const int w = tid >> 6;
  const int lr = l & 15, lg = l >> 4;
  const int bh = blockIdx.y;           // 0..95
  const int b = bh / 12, h = bh % 12;
  const int q0 = blockIdx.x * 128 + w * 32;  // this wave's first q row (within head)
  const bf16* Qh = Q + (size_t)bh * 65536;
  const bf16* Kh = K + (size_t)bh * 65536;
  const bf16* Vh = Vt + (size_t)bh * 65536;

  // Q fragments (A-operand): row = lr, k(d) = lg*8
  bf16x8 qf[2][2];
#pragma unroll
  for (int mi = 0; mi < 2; mi++)
#pragma unroll
    for (int ks = 0; ks < 2; ks++)
      qf[mi][ks] = *reinterpret_cast<const bf16x8*>(
          &Qh[(size_t)(q0 + mi * 16 + lr) * 64 + ks * 32 + lg * 8]);

  f32x4 o[2][4] = {};
  float mrun[2][4], lrun[2][4];
#pragma unroll
  for (int mi = 0; mi < 2; mi++)
#pragma unroll
    for (int r = 0; r < 4; r++) { mrun[mi][r] = -1e30f; lrun[mi][r] = 0.f; }

  for (int kt = 0; kt < 1024; kt += 128) {
    // ---- S = Q K^T for this 128-col tile ----
    f32x4 s[2][8] = {};
#pragma unroll
    for (int ni = 0; ni < 8; ni++) {
      bf16x8 kf0 = *reinterpret_cast<const bf16x8*>(
          &Kh[(size_t)(kt + ni * 16 + lr) * 64 + lg * 8]);
      bf16x8 kf1 = *reinterpret_cast<const bf16x8*>(
          &Kh[(size_t)(kt + ni * 16 + lr) * 64 + 32 + lg * 8]);
#pragma unroll
      for (int mi = 0; mi < 2; mi++) {
        s[mi][ni] = __builtin_amdgcn_mfma_f32_16x16x32_bf16(qf[mi][0], kf0, s[mi][ni], 0, 0, 0);
        s[mi][ni] = __builtin_amdgcn_mfma_f32_16x16x32_bf16(qf[mi][1], kf1, s[mi][ni], 0, 0, 0);
      }
    }
    // ---- online softmax (rows live across lr lanes; reduce over lane bits 0-3) ----
#pragma unroll
    for (int mi = 0; mi < 2; mi++) {
      float al[4];
#pragma unroll
      for (int r = 0; r < 4; r++) {
        float tm = s[mi][0][r];
#pragma unroll
        for (int ni = 1; ni < 8; ni++) tm = fmaxf(tm, s[mi][ni][r]);
        tm = fmaxf(tm, __shfl_xor(tm, 1));
        tm = fmaxf(tm, __shfl_xor(tm, 2));
        tm = fmaxf(tm, __shfl_xor(tm, 4));
        tm = fmaxf(tm, __shfl_xor(tm, 8));
        const float mn = fmaxf(mrun[mi][r], tm);
        const float a = __expf(mrun[mi][r] - mn);
        mrun[mi][r] = mn;
        al[r] = a;
        float rs = 0.f;
#pragma unroll
        for (int ni = 0; ni < 8; ni++) {
          const float p = __expf(s[mi][ni][r] - mn);
          s[mi][ni][r] = p;
          rs += p;
        }
        rs += __shfl_xor(rs, 1);
        rs += __shfl_xor(rs, 2);
        rs += __shfl_xor(rs, 4);
        rs += __shfl_xor(rs, 8);
        lrun[mi][r] = lrun[mi][r] * a + rs;
      }
#pragma unroll
      for (int di = 0; di < 4; di++)
#pragma unroll
        for (int r = 0; r < 4; r++) o[mi][di][r] *= al[r];
      // write P tile (C-layout -> LDS [q][k])
#pragma unroll
      for (int ni = 0; ni < 8; ni++)
#pragma unroll
        for (int r = 0; r < 4; r++)
          P_lds[w][mi * 16 + lg * 4 + r][ni * 16 + lr] = (bf16)s[mi][ni][r];
    }
    // ---- O += P V  (A = P from LDS, B = Vt rows, contiguous) ----
#pragma unroll
    for (int kk = 0; kk < 4; kk++) {
      bf16x8 vf[4];
#pragma unroll
      for (int di = 0; di < 4; di++)
        vf[di] = *reinterpret_cast<const bf16x8*>(
            &Vh[(size_t)(di * 16 + lr) * 1024 + kt + kk * 32 + lg * 8]);
#pragma unroll
      for (int mi = 0; mi < 2; mi++) {
        bf16x8 pf = *reinterpret_cast<const bf16x8*>(
            &P_lds[w][mi * 16 + lr][kk * 32 + lg * 8]);
#pragma unroll
        for (int di = 0; di < 4; di++)
          o[mi][di] = __builtin_amdgcn_mfma_f32_16x16x32_bf16(pf, vf[di], o[mi][di], 0, 0, 0);
      }
    }
  }

  // ---- normalize + store (bf16, [b, n, h*64+d]) ----
#pragma unroll
  for (int mi = 0; mi < 2; mi++)
#pragma unroll
    for (int di = 0; di < 4; di++)
#pragma unroll
      for (int r = 0; r < 4; r++) {
        const float val = o[mi][di][r] / lrun[mi][r];
        Out[(size_t)(b * 1024 + q0 + mi * 16 + lg * 4 + r) * 768 + h * 64 + di * 16 + lr] =
            (bf16)val;
      }
}

// ---------------- launch ------------------------------------------------------
extern "C" void kernel_launch(void* const* d_in, const int* in_sizes, int n_in,
                              void* d_out, int out_size, void* d_ws, size_t ws_size,
                              hipStream_t stream) {
  const float* x = (const float*)d_in[0];
  const float* w_qkv = (const float*)d_in[1];
  const float* w_fc = (const float*)d_in[2];
  const float* b_fc = (const float*)d_in[3];
  float* out = (float*)d_out;
  char* ws = (char*)d_ws;

  bf16* xb = (bf16*)(ws);                    // 8192x768        = 12582912 B
  bf16* wqkb = (bf16*)(ws + 12582912);       // 2304x768        = 3538944 B
  bf16* wfcb = (bf16*)(ws + 16121856);       // 768x768         = 1179648 B
  bf16* qb = (bf16*)(ws + 17301504);         // 96x1024x64      = 12582912 B
  bf16* kb = (bf16*)(ws + 29884416);         // 96x1024x64
  bf16* vtb = (bf16*)(ws + 42467328);        // 96x64x1024
  bf16* aob = (bf16*)(ws + 55050240);        // 8192x768
  // total ws use: 67633152 B (~64.5 MB)

  cvt_f32_bf16<<<2048, 256, 0, stream>>>(x, xb, 6291456 / 4);
  cvt_f32_bf16<<<1728, 256, 0, stream>>>(w_qkv, wqkb, 1769472 / 4);
  cvt_f32_bf16<<<576, 256, 0, stream>>>(w_fc, wfcb, 589824 / 4);

  gemm_bt<0><<<dim3(64, 18), 256, 0, stream>>>(xb, wqkb, 8192, 2304, 768,
                                               qb, kb, vtb, nullptr, nullptr);

  attn_kernel<<<dim3(8, 96), 256, 0, stream>>>(qb, kb, vtb, aob);

  gemm_bt<1><<<dim3(64, 6), 256, 0, stream>>>(aob, wfcb, 8192, 768, 768,
                                              nullptr, nullptr, nullptr, out, b_fc);
}

// Round 2
// 184.007 us; speedup vs baseline: 1.0415x; 1.0415x over previous
//
#include <hip/hip_runtime.h>
#include <cstdint>
#include <cstddef>

typedef __bf16 bf16;
typedef __bf16 bf16x4 __attribute__((ext_vector_type(4)));
typedef __bf16 bf16x8 __attribute__((ext_vector_type(8)));
typedef float f32x4 __attribute__((ext_vector_type(4)));
typedef float f32x16 __attribute__((ext_vector_type(16)));

typedef const __attribute__((address_space(1))) void* gas_ptr;
typedef __attribute__((address_space(3))) void* las_ptr;

#define GLOAD_LDS16(g, l) __builtin_amdgcn_global_load_lds((gas_ptr)(g), (las_ptr)(l), 16, 0, 0)

// ---------------- f32 -> bf16 convert (vectorized, grid-stride) ----------------
__global__ void cvt_f32_bf16(const float* __restrict__ in, bf16* __restrict__ out, int n4) {
  int i = blockIdx.x * blockDim.x + threadIdx.x;
  int stride = gridDim.x * blockDim.x;
  for (; i < n4; i += stride) {
    float4 v = reinterpret_cast<const float4*>(in)[i];
    bf16x4 o;
    o[0] = (bf16)v.x; o[1] = (bf16)v.y; o[2] = (bf16)v.z; o[3] = (bf16)v.w;
    reinterpret_cast<bf16x4*>(out)[i] = o;
  }
}

// ---------------- GEMM: C[M,N] = A[M,K] * B[N,K]^T  (both K-contiguous) --------
// MODE 0: QKV epilogue -> scatter to q[b,h,n,d], k[b,h,n,d], vT[b,h,d,n] (bf16)
// MODE 1: FC epilogue  -> out[m,e] = acc + bias[e] (f32)
template <int MODE>
__global__ __launch_bounds__(256, 2) void gemm_bt(
    const bf16* __restrict__ A, const bf16* __restrict__ B,
    int M, int N, int K,
    bf16* __restrict__ qb, bf16* __restrict__ kb, bf16* __restrict__ vtb,
    float* __restrict__ out, const float* __restrict__ bias) {
  constexpr int BK = 32;
  __shared__ bf16 ldsA[128 * BK];
  __shared__ bf16 ldsB[128 * BK];
  const int tid = threadIdx.x;
  const int l = tid & 63;
  const int w = tid >> 6;      // wave 0..3 (2x2)
  const int wr = w >> 1, wc = w & 1;
  const int lr = l & 15, lg = l >> 4;
  const int brow = blockIdx.x * 128;
  const int bcol = blockIdx.y * 128;

  const int srow = tid >> 2;
  const int scol = (tid & 3) * 8;
  const bf16* Ag0 = A + (size_t)(brow + srow) * K + scol;
  const bf16* Ag1 = A + (size_t)(brow + 64 + srow) * K + scol;
  const bf16* Bg0 = B + (size_t)(bcol + srow) * K + scol;
  const bf16* Bg1 = B + (size_t)(bcol + 64 + srow) * K + scol;
  bf16* la0 = &ldsA[tid * 8];
  bf16* la1 = &ldsA[2048 + tid * 8];
  bf16* lb0 = &ldsB[tid * 8];
  bf16* lb1 = &ldsB[2048 + tid * 8];

  f32x4 acc[4][4] = {};

  for (int k0 = 0; k0 < K; k0 += BK) {
    GLOAD_LDS16(Ag0 + k0, la0);
    GLOAD_LDS16(Ag1 + k0, la1);
    GLOAD_LDS16(Bg0 + k0, lb0);
    GLOAD_LDS16(Bg1 + k0, lb1);
    __syncthreads();
    bf16x8 af[4], bfr[4];
#pragma unroll
    for (int mi = 0; mi < 4; mi++)
      af[mi] = *reinterpret_cast<const bf16x8*>(&ldsA[(wr * 64 + mi * 16 + lr) * BK + lg * 8]);
#pragma unroll
    for (int ni = 0; ni < 4; ni++)
      bfr[ni] = *reinterpret_cast<const bf16x8*>(&ldsB[(wc * 64 + ni * 16 + lr) * BK + lg * 8]);
#pragma unroll
    for (int mi = 0; mi < 4; mi++)
#pragma unroll
      for (int ni = 0; ni < 4; ni++)
        acc[mi][ni] = __builtin_amdgcn_mfma_f32_16x16x32_bf16(af[mi], bfr[ni], acc[mi][ni], 0, 0, 0);
    __syncthreads();
  }

  // epilogue: C frag mapping col = lr, row = lg*4 + r
#pragma unroll
  for (int mi = 0; mi < 4; mi++) {
#pragma unroll
    for (int r = 0; r < 4; r++) {
      const int m = brow + wr * 64 + mi * 16 + lg * 4 + r;
      const int bb = m >> 10;        // batch
      const int npos = m & 1023;     // sequence pos
#pragma unroll
      for (int ni = 0; ni < 4; ni++) {
        const int e = bcol + wc * 64 + ni * 16 + lr;
        const float v = acc[mi][ni][r];
        if (MODE == 1) {
          out[(size_t)m * N + e] = v + bias[e];
        } else {
          if (e < 768) {
            const int h = e >> 6, d = e & 63;
            qb[(size_t)(bb * 12 + h) * 65536 + npos * 64 + d] = (bf16)v;
          } else if (e < 1536) {
            const int ee = e - 768;
            const int h = ee >> 6, d = ee & 63;
            kb[(size_t)(bb * 12 + h) * 65536 + npos * 64 + d] = (bf16)v;
          } else {
            const int ee = e - 1536;
            const int h = ee >> 6, d = ee & 63;
            vtb[(size_t)(bb * 12 + h) * 65536 + d * 1024 + npos] = (bf16)v;
          }
        }
      }
    }
  }
}

// ---------------- Flash attention, swapped-QK^T, 32x32 MFMA, zero LDS ---------
// Q,K: [96][1024][64] bf16 ; Vt: [96][64][1024] bf16 ; Out bf16 [8][1024][768]
// grid (96 heads, 8 qtiles) so a head's 8 blocks share an XCD (96 % 8 == 0).
// 256 threads = 4 waves; wave w owns 32 q rows. Each lane owns ONE q column
// (q = q0 + (lane&31)); lanes l and l+32 hold complementary k-rows of S^T.
__global__ __launch_bounds__(256, 3) void attn_kernel(
    const bf16* __restrict__ Q, const bf16* __restrict__ K,
    const bf16* __restrict__ Vt, bf16* __restrict__ Out) {
  const int tid = threadIdx.x;
  const int l = tid & 63;
  const int w = tid >> 6;
  const int ql = l & 31;         // q column within wave tile
  const int hi = l >> 5;
  const int bh = blockIdx.x;     // 0..95
  const int b = bh / 12, h = bh % 12;
  const int q0 = blockIdx.y * 128 + w * 32;
  const bf16* Qh = Q + (size_t)bh * 65536;
  const bf16* Kh = K + (size_t)bh * 65536;
  const bf16* Vh = Vt + (size_t)bh * 65536;

  // Q as B-operand of S^T = K.Q^T : col=q=lane&31, contraction d = s*16+hi*8+j
  bf16x8 qf[4];
#pragma unroll
  for (int s = 0; s < 4; s++)
    qf[s] = *reinterpret_cast<const bf16x8*>(&Qh[(size_t)(q0 + ql) * 64 + s * 16 + hi * 8]);

  f32x16 o[2] = {};              // O^T accum: two 32-d tiles, col=q
  float m = -1e30f, lsum = 0.f;  // per-lane scalar stats (one q per lane)

  for (int kt = 0; kt < 1024; kt += 64) {
    // ---- S^T tile: 2 x (32k x 32q), contraction d=64 ----
    f32x16 st[2] = {};
#pragma unroll
    for (int kb = 0; kb < 2; kb++) {
#pragma unroll
      for (int s = 0; s < 4; s++) {
        bf16x8 kf = *reinterpret_cast<const bf16x8*>(
            &Kh[(size_t)(kt + kb * 32 + ql) * 64 + s * 16 + hi * 8]);
        st[kb] = __builtin_amdgcn_mfma_f32_32x32x16_bf16(kf, qf[s], st[kb], 0, 0, 0);
      }
    }
    // ---- issue V loads early (latency hides under softmax VALU) ----
    bf16x8 vf[4][2];
#pragma unroll
    for (int t = 0; t < 4; t++)
#pragma unroll
      for (int dh = 0; dh < 2; dh++)
        vf[t][dh] = *reinterpret_cast<const bf16x8*>(
            &Vh[(size_t)(dh * 32 + ql) * 1024 + kt + t * 16 + hi * 8]);

    // ---- lane-local online softmax over this lane's 32 k-values ----
    float tm = st[0][0];
#pragma unroll
    for (int r = 1; r < 16; r++) tm = fmaxf(tm, st[0][r]);
#pragma unroll
    for (int r = 0; r < 16; r++) tm = fmaxf(tm, st[1][r]);
    tm = fmaxf(tm, __shfl_xor(tm, 32));
    const float mn = fmaxf(m, tm);
    const float a = __expf(m - mn);
    m = mn;
    float rs = 0.f;
#pragma unroll
    for (int kb = 0; kb < 2; kb++)
#pragma unroll
      for (int r = 0; r < 16; r++) {
        const float p = __expf(st[kb][r] - mn);
        st[kb][r] = p;
        rs += p;
      }
    rs += __shfl_xor(rs, 32);
    lsum = lsum * a + rs;
#pragma unroll
    for (int dh = 0; dh < 2; dh++)
#pragma unroll
      for (int r = 0; r < 16; r++) o[dh][r] *= a;

    // ---- P^T -> B-fragments via cvt_pk + permlane32_swap; O^T += V^T P^T ----
#pragma unroll
    for (int t = 0; t < 4; t++) {
      const int kb = t >> 1, c8 = (t & 1) * 8;
      uint32_t wA0, wA1, wB0, wB1;
      asm("v_cvt_pk_bf16_f32 %0, %1, %2" : "=v"(wA0) : "v"(st[kb][c8 + 0]), "v"(st[kb][c8 + 1]));
      asm("v_cvt_pk_bf16_f32 %0, %1, %2" : "=v"(wA1) : "v"(st[kb][c8 + 2]), "v"(st[kb][c8 + 3]));
      asm("v_cvt_pk_bf16_f32 %0, %1, %2" : "=v"(wB0) : "v"(st[kb][c8 + 4]), "v"(st[kb][c8 + 5]));
      asm("v_cvt_pk_bf16_f32 %0, %1, %2" : "=v"(wB1) : "v"(st[kb][c8 + 6]), "v"(st[kb][c8 + 7]));
      // (word0,word2) = swap(wA0,wB0); (word1,word3) = swap(wA1,wB1)
      asm("v_permlane32_swap_b32 %0, %1" : "+v"(wA0), "+v"(wB0));
      asm("v_permlane32_swap_b32 %0, %1" : "+v"(wA1), "+v"(wB1));
      union { uint32_t u[4]; bf16x8 v; } pf;
      pf.u[0] = wA0; pf.u[1] = wA1; pf.u[2] = wB0; pf.u[3] = wB1;
#pragma unroll
      for (int dh = 0; dh < 2; dh++)
        o[dh] = __builtin_amdgcn_mfma_f32_32x32x16_bf16(vf[t][dh], pf.v, o[dh], 0, 0, 0);
    }
  }

  // ---- normalize + store: Out[b, q0+ql, h*64 + d], 8B vector stores ----
  const float rl = 1.0f / lsum;
  bf16* orow = Out + (size_t)(b * 1024 + q0 + ql) * 768 + h * 64;
#pragma unroll
  for (int dh = 0; dh < 2; dh++)
#pragma unroll
    for (int rq = 0; rq < 4; rq++) {
      union { ushort us[4]; uint2 v; } pk;
#pragma unroll
      for (int i = 0; i < 4; i++) {
        const bf16 hv = (bf16)(o[dh][rq * 4 + i] * rl);
        pk.us[i] = __builtin_bit_cast(ushort, hv);
      }
      *reinterpret_cast<uint2*>(&orow[dh * 32 + rq * 8 + hi * 4]) = pk.v;
    }
}

// ---------------- launch ------------------------------------------------------
extern "C" void kernel_launch(void* const* d_in, const int* in_sizes, int n_in,
                              void* d_out, int out_size, void* d_ws, size_t ws_size,
                              hipStream_t stream) {
  const float* x = (const float*)d_in[0];
  const float* w_qkv = (const float*)d_in[1];
  const float* w_fc = (const float*)d_in[2];
  const float* b_fc = (const float*)d_in[3];
  float* out = (float*)d_out;
  char* ws = (char*)d_ws;

  bf16* xb = (bf16*)(ws);                    // 8192x768
  bf16* wqkb = (bf16*)(ws + 12582912);       // 2304x768
  bf16* wfcb = (bf16*)(ws + 16121856);       // 768x768
  bf16* qb = (bf16*)(ws + 17301504);         // 96x1024x64
  bf16* kb = (bf16*)(ws + 29884416);         // 96x1024x64
  bf16* vtb = (bf16*)(ws + 42467328);        // 96x64x1024
  bf16* aob = (bf16*)(ws + 55050240);        // 8192x768

  cvt_f32_bf16<<<2048, 256, 0, stream>>>(x, xb, 6291456 / 4);
  cvt_f32_bf16<<<1728, 256, 0, stream>>>(w_qkv, wqkb, 1769472 / 4);
  cvt_f32_bf16<<<576, 256, 0, stream>>>(w_fc, wfcb, 589824 / 4);

  gemm_bt<0><<<dim3(64, 18), 256, 0, stream>>>(xb, wqkb, 8192, 2304, 768,
                                               qb, kb, vtb, nullptr, nullptr);

  attn_kernel<<<dim3(96, 8), 256, 0, stream>>>(qb, kb, vtb, aob);

  gemm_bt<1><<<dim3(64, 6), 256, 0, stream>>>(aob, wfcb, 8192, 768, 768,
                                              nullptr, nullptr, nullptr, out, b_fc);
}